// Round 8
// baseline (1115.091 us; speedup 1.0000x reference)
//
#include <hip/hip_runtime.h>
#include <stdint.h>

#define N_NODES 100000
#define N_EDGES 1600000
#define EAD 7
#define H 64
#define LAT 32
#define NG 512
#define NC 6
#define NZ (N_NODES * LAT)

#define NB_SCAN 391            // ceil(N_NODES/256)
#define NPW1 4                 // nodes per wave, conv1 (6250 blocks)
#define NPWM 5                 // nodes per wave, conv2_heads (2500 blocks x 8 waves)

static_assert(N_NODES % (4 * NPW1) == 0, "conv1 grid exact");
static_assert(N_NODES % (8 * NPWM) == 0, "conv2_heads grid exact");
static_assert(N_EDGES % 256 == 0, "edge grid exact");

// ---------------- Threefry-2x32-20, key = (0, 42)  (jax.random.key(42)) ----
__device__ __forceinline__ void threefry2x32_42(uint32_t& x0, uint32_t& x1) {
    const uint32_t k0 = 0u, k1 = 42u;
    const uint32_t k2 = k0 ^ k1 ^ 0x1BD11BDAu;
    x0 += k0; x1 += k1;
#define TF_ROUND(r) { x0 += x1; x1 = (x1 << (r)) | (x1 >> (32 - (r))); x1 ^= x0; }
    TF_ROUND(13) TF_ROUND(15) TF_ROUND(26) TF_ROUND(6)
    x0 += k1; x1 += k2 + 1u;
    TF_ROUND(17) TF_ROUND(29) TF_ROUND(16) TF_ROUND(24)
    x0 += k2; x1 += k0 + 2u;
    TF_ROUND(13) TF_ROUND(15) TF_ROUND(26) TF_ROUND(6)
    x0 += k0; x1 += k1 + 3u;
    TF_ROUND(17) TF_ROUND(29) TF_ROUND(16) TF_ROUND(24)
    x0 += k1; x1 += k2 + 4u;
    TF_ROUND(13) TF_ROUND(15) TF_ROUND(26) TF_ROUND(6)
    x0 += k2; x1 += k0 + 5u;
#undef TF_ROUND
}

// XLA f32 ErfInv (Giles): matches jax.lax.erf_inv on f32
__device__ __forceinline__ float erfinv_f32(float x) {
    float w = -log1pf(-x * x);
    float p;
    if (w < 5.0f) {
        w = w - 2.5f;
        p = 2.81022636e-08f;
        p = fmaf(p, w, 3.43273939e-07f);
        p = fmaf(p, w, -3.5233877e-06f);
        p = fmaf(p, w, -4.39150654e-06f);
        p = fmaf(p, w, 0.00021858087f);
        p = fmaf(p, w, -0.00125372503f);
        p = fmaf(p, w, -0.00417768164f);
        p = fmaf(p, w, 0.246640727f);
        p = fmaf(p, w, 1.50140941f);
    } else {
        w = sqrtf(w) - 3.0f;
        p = -0.000200214257f;
        p = fmaf(p, w, 0.000100950558f);
        p = fmaf(p, w, 0.00134934322f);
        p = fmaf(p, w, -0.00367342844f);
        p = fmaf(p, w, 0.00573950773f);
        p = fmaf(p, w, -0.0076224613f);
        p = fmaf(p, w, 0.00943887047f);
        p = fmaf(p, w, 1.00167406f);
        p = fmaf(p, w, 2.83297682f);
    }
    return p * x;
}

// ---------------- CSR build: histogram of dst -------------------------------
__global__ void hist_k(const int* __restrict__ dst, int* __restrict__ deg) {
    int e = blockIdx.x * blockDim.x + threadIdx.x;
    if (e < N_EDGES) atomicAdd(&deg[dst[e]], 1);
}

// ---------------- CSR build: 3-pass exclusive scan over deg -----------------
__global__ void scan1_k(const int* __restrict__ deg, int* __restrict__ bsum) {
    __shared__ int sv[256];
    int t = threadIdx.x, i = blockIdx.x * 256 + t;
    sv[t] = (i < N_NODES) ? deg[i] : 0;
    __syncthreads();
    for (int o = 128; o > 0; o >>= 1) {
        if (t < o) sv[t] += sv[t + o];
        __syncthreads();
    }
    if (t == 0) bsum[blockIdx.x] = sv[0];
}

__global__ void scan2_k(int* __restrict__ bsum) {
    __shared__ int sv[512];
    int t = threadIdx.x;
    int v = (t < NB_SCAN) ? bsum[t] : 0;
    sv[t] = v;
    __syncthreads();
    for (int o = 1; o < 512; o <<= 1) {
        int a = (t >= o) ? sv[t - o] : 0;
        __syncthreads();
        sv[t] += a;
        __syncthreads();
    }
    if (t < NB_SCAN) bsum[t] = sv[t] - v;   // exclusive block offsets
}

__global__ void scan3_k(const int* __restrict__ deg, const int* __restrict__ bsum,
                        int* __restrict__ off, int* __restrict__ cur) {
    __shared__ int sv[256];
    int t = threadIdx.x, i = blockIdx.x * 256 + t;
    int v = (i < N_NODES) ? deg[i] : 0;
    sv[t] = v;
    __syncthreads();
    for (int o = 1; o < 256; o <<= 1) {
        int a = (t >= o) ? sv[t - o] : 0;
        __syncthreads();
        sv[t] += a;
        __syncthreads();
    }
    if (i < N_NODES) {
        int s = bsum[blockIdx.x] + sv[t] - v;
        off[i] = s;
        cur[i] = s;   // cursor; after scatter_k, cur[i] == segment end
    }
}

// ---------------- CSR build: scatter edges into dst-sorted order ------------
__global__ void scatter_k(const float* __restrict__ x, const int* __restrict__ src,
                          const int* __restrict__ dst, const float* __restrict__ ea,
                          const float* __restrict__ We1, const float* __restrict__ be1,
                          int* __restrict__ cur, int2* __restrict__ rec8,
                          float* __restrict__ m1s) {
    int e = blockIdx.x * blockDim.x + threadIdx.x;
    if (e >= N_EDGES) return;
    int s = src[e], d = dst[e];
    const float* ep = ea + (size_t)e * EAD;
    float p = be1[0];
#pragma unroll
    for (int k = 0; k < EAD; k++) p = fmaf(ep[k], We1[k], p);
    float m = x[s] + p;
    m = m > 0.0f ? m : 0.0f;
    int pos = atomicAdd(&cur[d], 1);
    rec8[pos] = make_int2(s, e);
    m1s[pos] = m;
}

// ---------------- conv1: segmented sum of m1 + fused MLP 1->64->64 ----------
__global__ void conv1_fused(const float* __restrict__ x, const float* __restrict__ m1s,
                            const int* __restrict__ off, const int* __restrict__ cur,
                            const float* __restrict__ W11, const float* __restrict__ b11,
                            const float* __restrict__ W12, const float* __restrict__ b12,
                            const float* __restrict__ eps1, float* __restrict__ hA) {
    __shared__ float sW12[H * H];
    __shared__ float stg[4][H];
    int tid = threadIdx.x;
    for (int i = tid; i < H * H; i += 256) sW12[i] = W12[i];
    int w = tid >> 6, lane = tid & 63;
    float rW11 = W11[lane], rb11 = b11[lane], rb12 = b12[lane], er = eps1[0];
    __syncthreads();
    int n0 = (blockIdx.x * 4 + w) * NPW1;
#pragma unroll
    for (int ni = 0; ni < NPW1; ni++) {
        int n = n0 + ni;
        int g0 = off[n], g1 = cur[n];
        float agg = 0.0f;
        for (int j = g0 + lane; j < g1; j += 64) agg += m1s[j];
#pragma unroll
        for (int o = 32; o > 0; o >>= 1) agg += __shfl_xor(agg, o, 64);
        float xv = x[n];
        float h1 = fmaf(er, xv, xv) + agg;
        float t = fmaf(h1, rW11, rb11);
        t = t > 0.0f ? t : 0.0f;
        stg[w][lane] = t;                  // intra-wave staging (lockstep)
        float acc = rb12;
#pragma unroll
        for (int j = 0; j < H; j++) acc = fmaf(stg[w][j], sW12[j * H + lane], acc);
        hA[(size_t)n * H + lane] = acc > 0.0f ? acc : 0.0f;
    }
}

// ---------------- conv2+heads mega-kernel, occupancy-shaped -----------------
// 512-thread blocks (8 waves share ONE 32KB W21/W22 LDS copy). 50KB LDS ->
// 3 blocks/CU = 24 waves/CU (vs 8 before). Head weights (16KB) read from
// global (L1/L2-resident). z/mu/lv packed to float4 via shfl-transpose and
// stored per node (128B contiguous per array) - no szout buffer.
// z accumulated into zsum[G][LAT] atomics for the pool.
__global__ void conv2_heads(const float* __restrict__ hA, const int2* __restrict__ rec8,
                            const float* __restrict__ ea, const int* __restrict__ batch,
                            const int* __restrict__ off, const int* __restrict__ cur,
                            const float* __restrict__ We2, const float* __restrict__ be2,
                            const float* __restrict__ W21, const float* __restrict__ b21,
                            const float* __restrict__ W22, const float* __restrict__ b22,
                            const float* __restrict__ eps2,
                            const float* __restrict__ Wmu, const float* __restrict__ bmu,
                            const float* __restrict__ Wlv, const float* __restrict__ blv,
                            float4* __restrict__ out4, float* __restrict__ zsum) {
    __shared__ float sW21[H * H], sW22[H * H];        // 32 KB, shared by 8 waves
    __shared__ float4 srec[8][64][2];                 // 16 KB
    __shared__ float stg[8][H];                       //  2 KB
    int tid = threadIdx.x;
    for (int i = tid; i < H * H; i += 512) { sW21[i] = W21[i]; sW22[i] = W22[i]; }
    int w = tid >> 6, lane = tid & 63;
    float rW[EAD];
#pragma unroll
    for (int k = 0; k < EAD; k++) rW[k] = We2[k * H + lane];
    float rbe2 = be2[lane], rb21 = b21[lane], rb22 = b22[lane], er = eps2[0];
    int l = lane & 31;
    float rbh = (lane < LAT) ? bmu[l] : blv[l];
    const float* __restrict__ Wh = (lane < LAT) ? Wmu : Wlv;   // global, L1/L2
    __syncthreads();

    int n0 = (blockIdx.x * 8 + w) * NPWM;
    int eend = cur[n0 + NPWM - 1];
    int sbase = -(1 << 30);

    auto restage = [&](int g) {
        sbase = g;
        int cnt = eend - g; cnt = cnt > 64 ? 64 : cnt;
        float a0 = 0, a1 = 0, a2 = 0, a3 = 0, a4 = 0, a5 = 0, a6 = 0;
        int s = 0;
        if (lane < cnt) {
            int2 r = rec8[g + lane];
            s = r.x;
            const float* ep = ea + (size_t)r.y * EAD;
            a0 = ep[0]; a1 = ep[1]; a2 = ep[2]; a3 = ep[3];
            a4 = ep[4]; a5 = ep[5]; a6 = ep[6];
        }
        srec[w][lane][0] = make_float4(a0, a1, a2, a3);
        srec[w][lane][1] = make_float4(a4, a5, a6, __int_as_float(s));
    };

    for (int ni = 0; ni < NPWM; ni++) {
        int n = n0 + ni;
        int g = off[n], gend = cur[n];
        float acc = 0.0f;
        while (g + 4 <= gend) {
            if (g + 4 > sbase + 64) restage(g);
            int b = g - sbase;
            float4 A0 = srec[w][b + 0][0], B0 = srec[w][b + 0][1];
            float4 A1 = srec[w][b + 1][0], B1 = srec[w][b + 1][1];
            float4 A2 = srec[w][b + 2][0], B2 = srec[w][b + 2][1];
            float4 A3 = srec[w][b + 3][0], B3 = srec[w][b + 3][1];
            int s0 = __builtin_amdgcn_readfirstlane(__float_as_int(B0.w));
            int s1 = __builtin_amdgcn_readfirstlane(__float_as_int(B1.w));
            int s2 = __builtin_amdgcn_readfirstlane(__float_as_int(B2.w));
            int s3 = __builtin_amdgcn_readfirstlane(__float_as_int(B3.w));
            float hv0 = hA[(size_t)s0 * H + lane];
            float hv1 = hA[(size_t)s1 * H + lane];
            float hv2 = hA[(size_t)s2 * H + lane];
            float hv3 = hA[(size_t)s3 * H + lane];
            float p0 = rbe2, p1 = rbe2, p2 = rbe2, p3 = rbe2;
            p0 = fmaf(A0.x, rW[0], p0); p0 = fmaf(A0.y, rW[1], p0);
            p0 = fmaf(A0.z, rW[2], p0); p0 = fmaf(A0.w, rW[3], p0);
            p0 = fmaf(B0.x, rW[4], p0); p0 = fmaf(B0.y, rW[5], p0);
            p0 = fmaf(B0.z, rW[6], p0);
            p1 = fmaf(A1.x, rW[0], p1); p1 = fmaf(A1.y, rW[1], p1);
            p1 = fmaf(A1.z, rW[2], p1); p1 = fmaf(A1.w, rW[3], p1);
            p1 = fmaf(B1.x, rW[4], p1); p1 = fmaf(B1.y, rW[5], p1);
            p1 = fmaf(B1.z, rW[6], p1);
            p2 = fmaf(A2.x, rW[0], p2); p2 = fmaf(A2.y, rW[1], p2);
            p2 = fmaf(A2.z, rW[2], p2); p2 = fmaf(A2.w, rW[3], p2);
            p2 = fmaf(B2.x, rW[4], p2); p2 = fmaf(B2.y, rW[5], p2);
            p2 = fmaf(B2.z, rW[6], p2);
            p3 = fmaf(A3.x, rW[0], p3); p3 = fmaf(A3.y, rW[1], p3);
            p3 = fmaf(A3.z, rW[2], p3); p3 = fmaf(A3.w, rW[3], p3);
            p3 = fmaf(B3.x, rW[4], p3); p3 = fmaf(B3.y, rW[5], p3);
            p3 = fmaf(B3.z, rW[6], p3);
            acc += fmaxf(hv0 + p0, 0.0f);
            acc += fmaxf(hv1 + p1, 0.0f);
            acc += fmaxf(hv2 + p2, 0.0f);
            acc += fmaxf(hv3 + p3, 0.0f);
            g += 4;
        }
        while (g < gend) {
            if (g >= sbase + 64) restage(g);
            int b = g - sbase;
            float4 A = srec[w][b][0], B = srec[w][b][1];
            int s = __builtin_amdgcn_readfirstlane(__float_as_int(B.w));
            float hv = hA[(size_t)s * H + lane];
            float p = rbe2;
            p = fmaf(A.x, rW[0], p); p = fmaf(A.y, rW[1], p);
            p = fmaf(A.z, rW[2], p); p = fmaf(A.w, rW[3], p);
            p = fmaf(B.x, rW[4], p); p = fmaf(B.y, rW[5], p);
            p = fmaf(B.z, rW[6], p);
            acc += fmaxf(hv + p, 0.0f);
            g++;
        }
        // fused 2-layer MLP (wave-synchronous LDS staging)
        float hself = hA[(size_t)n * H + lane];
        float h2 = fmaf(er, hself, hself) + acc;
        stg[w][lane] = h2;
        float t = rb21;
#pragma unroll
        for (int j = 0; j < H; j++) t = fmaf(stg[w][j], sW21[j * H + lane], t);
        t = t > 0.0f ? t : 0.0f;
        stg[w][lane] = t;
        float o2 = rb22;
#pragma unroll
        for (int j = 0; j < H; j++) o2 = fmaf(stg[w][j], sW22[j * H + lane], o2);
        o2 = o2 > 0.0f ? o2 : 0.0f;
        stg[w][lane] = o2;                 // hB row, lane = feature
        // heads GEMV: lanes 0-31 mu[l], lanes 32-63 lv[l]; weights from global
        float v = rbh;
#pragma unroll 16
        for (int j = 0; j < H; j++) v = fmaf(stg[w][j], Wh[j * LAT + l], v);
        float o = __shfl(v, lane ^ 32);    // counterpart
        float muv = (lane < LAT) ? v : o;
        float lvv = (lane < LAT) ? o : v;
        int i = n * LAT + l;
        uint32_t x0 = 0u, x1 = (uint32_t)i;
        threefry2x32_42(x0, x1);
        uint32_t bits = x0 ^ x1;
        float f = __uint_as_float((bits >> 9) | 0x3F800000u) - 1.0f;
        const float lo = -0.99999994f;
        float u = fmaxf(lo, fmaf(f, 2.0f, lo));
        float noise = 1.41421356237309515f * erfinv_f32(u);
        float z = fmaf(noise, expf(0.5f * lvv), muv);
        if (lane < LAT) atomicAdd(&zsum[batch[n] * LAT + l], z);
        // shfl-transpose pack: lane k<8 gathers elements 4k..4k+3 (lanes<32)
        int sl = (lane << 2) & 63;
        float4 zv = make_float4(__shfl(z, sl), __shfl(z, sl + 1),
                                __shfl(z, sl + 2), __shfl(z, sl + 3));
        float4 mv = make_float4(__shfl(muv, sl), __shfl(muv, sl + 1),
                                __shfl(muv, sl + 2), __shfl(muv, sl + 3));
        float4 lv4 = make_float4(__shfl(lvv, sl), __shfl(lvv, sl + 1),
                                 __shfl(lvv, sl + 2), __shfl(lvv, sl + 3));
        if (lane < 8) {
            size_t o8 = (size_t)n * 8 + lane;
            out4[o8] = zv;
            out4[(size_t)(NZ / 4) + o8] = mv;
            out4[2 * (size_t)(NZ / 4) + o8] = lv4;
        }
    }
}

// ---------------- pool + logits from zsum; batch SORTED ---------------------
__global__ void pool2_k(const float* __restrict__ zsum, const int* __restrict__ batch,
                        const float* __restrict__ Wc, const float* __restrict__ bc,
                        float* __restrict__ out) {
    __shared__ float emb[LAT];
    int g = blockIdx.x, tid = threadIdx.x;
    int lo = 0, hi = N_NODES;
    while (lo < hi) { int mid = (lo + hi) >> 1; if (batch[mid] < g) lo = mid + 1; else hi = mid; }
    int start = lo;
    hi = N_NODES;
    while (lo < hi) { int mid = (lo + hi) >> 1; if (batch[mid] < g + 1) lo = mid + 1; else hi = mid; }
    int end = lo;
    if (tid < LAT) {
        float invc = 1.0f / fmaxf((float)(end - start), 1.0f);
        emb[tid] = zsum[g * LAT + tid] * invc;
    }
    __syncthreads();
    if (tid < NC) {
        float r = bc[tid];
#pragma unroll
        for (int l = 0; l < LAT; l++) r = fmaf(emb[l], Wc[l * NC + tid], r);
        out[g * NC + tid] = r;
    }
}

extern "C" void kernel_launch(void* const* d_in, const int* in_sizes, int n_in,
                              void* d_out, int out_size, void* d_ws, size_t ws_size,
                              hipStream_t stream) {
    const float* x     = (const float*)d_in[0];
    const int*   ei    = (const int*)d_in[1];
    const float* ea    = (const float*)d_in[2];
    const int*   batch = (const int*)d_in[3];
    const float* We1   = (const float*)d_in[4];
    const float* be1   = (const float*)d_in[5];
    const float* W11   = (const float*)d_in[6];
    const float* b11   = (const float*)d_in[7];
    const float* W12   = (const float*)d_in[8];
    const float* b12   = (const float*)d_in[9];
    const float* eps1  = (const float*)d_in[10];
    const float* We2   = (const float*)d_in[11];
    const float* be2   = (const float*)d_in[12];
    const float* W21   = (const float*)d_in[13];
    const float* b21   = (const float*)d_in[14];
    const float* W22   = (const float*)d_in[15];
    const float* b22   = (const float*)d_in[16];
    const float* eps2  = (const float*)d_in[17];
    const float* Wmu   = (const float*)d_in[18];
    const float* bmu   = (const float*)d_in[19];
    const float* Wlv   = (const float*)d_in[20];
    const float* blv   = (const float*)d_in[21];
    const float* Wc    = (const float*)d_in[22];
    const float* bc    = (const float*)d_in[23];

    // ws layout (46.07 MB, inside the proven 51.6 MB budget):
    //   [zsum G*LAT]                          0.065 MB (zeroed each launch)
    //   [deg N][off N][cur N][bsum 512]       1.20 MB
    //   [rec8 E int2]                        12.80 MB
    //   [m1s E float]                         6.40 MB
    //   [hA  N*H float]                      25.60 MB
    float* zsum = (float*)d_ws;
    int*   deg  = (int*)d_ws + NG * LAT;
    int*   off  = deg + N_NODES;
    int*   cur  = off + N_NODES;
    int*   bsum = cur + N_NODES;
    int2*  rec8 = (int2*)(bsum + 512);
    float* m1s  = (float*)(rec8 + N_EDGES);
    float* hA   = m1s + N_EDGES;
    float* outf = (float*)d_out;

    // zero zsum + deg (contiguous)
    hipMemsetAsync(d_ws, 0, (size_t)(NG * LAT + N_NODES) * sizeof(float), stream);

    const int* src = ei;
    const int* dst = ei + N_EDGES;

    hist_k<<<N_EDGES / 256, 256, 0, stream>>>(dst, deg);
    scan1_k<<<NB_SCAN, 256, 0, stream>>>(deg, bsum);
    scan2_k<<<1, 512, 0, stream>>>(bsum);
    scan3_k<<<NB_SCAN, 256, 0, stream>>>(deg, bsum, off, cur);
    scatter_k<<<N_EDGES / 256, 256, 0, stream>>>(x, src, dst, ea, We1, be1, cur, rec8, m1s);
    conv1_fused<<<N_NODES / (4 * NPW1), 256, 0, stream>>>(
        x, m1s, off, cur, W11, b11, W12, b12, eps1, hA);
    conv2_heads<<<N_NODES / (8 * NPWM), 512, 0, stream>>>(
        hA, rec8, ea, batch, off, cur, We2, be2, W21, b21, W22, b22, eps2,
        Wmu, bmu, Wlv, blv, (float4*)outf, zsum);
    pool2_k<<<NG, 64, 0, stream>>>(zsum, batch, Wc, bc, outf + 3 * (size_t)NZ);
}

// Round 9
// 1026.202 us; speedup vs baseline: 1.0866x; 1.0866x over previous
//
#include <hip/hip_runtime.h>
#include <stdint.h>

#define N_NODES 100000
#define N_EDGES 1600000
#define EAD 7
#define H 64
#define LAT 32
#define NG 512
#define NC 6
#define NZ (N_NODES * LAT)

#define NB_SCAN 391            // ceil(N_NODES/256)
#define NPW1 4                 // nodes per wave, conv1 (6250 blocks)
#define NPWM 8                 // nodes per wave, conv2_heads (3125 blocks x 4 waves)

static_assert(N_NODES % (4 * NPW1) == 0, "conv1 grid exact");
static_assert(N_NODES % (4 * NPWM) == 0, "conv2_heads grid exact");
static_assert(N_EDGES % 256 == 0, "edge grid exact");

// ---------------- Threefry-2x32-20, key = (0, 42)  (jax.random.key(42)) ----
__device__ __forceinline__ void threefry2x32_42(uint32_t& x0, uint32_t& x1) {
    const uint32_t k0 = 0u, k1 = 42u;
    const uint32_t k2 = k0 ^ k1 ^ 0x1BD11BDAu;
    x0 += k0; x1 += k1;
#define TF_ROUND(r) { x0 += x1; x1 = (x1 << (r)) | (x1 >> (32 - (r))); x1 ^= x0; }
    TF_ROUND(13) TF_ROUND(15) TF_ROUND(26) TF_ROUND(6)
    x0 += k1; x1 += k2 + 1u;
    TF_ROUND(17) TF_ROUND(29) TF_ROUND(16) TF_ROUND(24)
    x0 += k2; x1 += k0 + 2u;
    TF_ROUND(13) TF_ROUND(15) TF_ROUND(26) TF_ROUND(6)
    x0 += k0; x1 += k1 + 3u;
    TF_ROUND(17) TF_ROUND(29) TF_ROUND(16) TF_ROUND(24)
    x0 += k1; x1 += k2 + 4u;
    TF_ROUND(13) TF_ROUND(15) TF_ROUND(26) TF_ROUND(6)
    x0 += k2; x1 += k0 + 5u;
#undef TF_ROUND
}

// XLA f32 ErfInv (Giles): matches jax.lax.erf_inv on f32
__device__ __forceinline__ float erfinv_f32(float x) {
    float w = -log1pf(-x * x);
    float p;
    if (w < 5.0f) {
        w = w - 2.5f;
        p = 2.81022636e-08f;
        p = fmaf(p, w, 3.43273939e-07f);
        p = fmaf(p, w, -3.5233877e-06f);
        p = fmaf(p, w, -4.39150654e-06f);
        p = fmaf(p, w, 0.00021858087f);
        p = fmaf(p, w, -0.00125372503f);
        p = fmaf(p, w, -0.00417768164f);
        p = fmaf(p, w, 0.246640727f);
        p = fmaf(p, w, 1.50140941f);
    } else {
        w = sqrtf(w) - 3.0f;
        p = -0.000200214257f;
        p = fmaf(p, w, 0.000100950558f);
        p = fmaf(p, w, 0.00134934322f);
        p = fmaf(p, w, -0.00367342844f);
        p = fmaf(p, w, 0.00573950773f);
        p = fmaf(p, w, -0.0076224613f);
        p = fmaf(p, w, 0.00943887047f);
        p = fmaf(p, w, 1.00167406f);
        p = fmaf(p, w, 2.83297682f);
    }
    return p * x;
}

// ---------------- CSR build: histogram of dst -------------------------------
__global__ void hist_k(const int* __restrict__ dst, int* __restrict__ deg) {
    int e = blockIdx.x * blockDim.x + threadIdx.x;
    if (e < N_EDGES) atomicAdd(&deg[dst[e]], 1);
}

// ---------------- CSR build: 3-pass exclusive scan over deg -----------------
__global__ void scan1_k(const int* __restrict__ deg, int* __restrict__ bsum) {
    __shared__ int sv[256];
    int t = threadIdx.x, i = blockIdx.x * 256 + t;
    sv[t] = (i < N_NODES) ? deg[i] : 0;
    __syncthreads();
    for (int o = 128; o > 0; o >>= 1) {
        if (t < o) sv[t] += sv[t + o];
        __syncthreads();
    }
    if (t == 0) bsum[blockIdx.x] = sv[0];
}

__global__ void scan2_k(int* __restrict__ bsum) {
    __shared__ int sv[512];
    int t = threadIdx.x;
    int v = (t < NB_SCAN) ? bsum[t] : 0;
    sv[t] = v;
    __syncthreads();
    for (int o = 1; o < 512; o <<= 1) {
        int a = (t >= o) ? sv[t - o] : 0;
        __syncthreads();
        sv[t] += a;
        __syncthreads();
    }
    if (t < NB_SCAN) bsum[t] = sv[t] - v;   // exclusive block offsets
}

__global__ void scan3_k(const int* __restrict__ deg, const int* __restrict__ bsum,
                        int* __restrict__ off, int* __restrict__ cur) {
    __shared__ int sv[256];
    int t = threadIdx.x, i = blockIdx.x * 256 + t;
    int v = (i < N_NODES) ? deg[i] : 0;
    sv[t] = v;
    __syncthreads();
    for (int o = 1; o < 256; o <<= 1) {
        int a = (t >= o) ? sv[t - o] : 0;
        __syncthreads();
        sv[t] += a;
        __syncthreads();
    }
    if (i < N_NODES) {
        int s = bsum[blockIdx.x] + sv[t] - v;
        off[i] = s;
        cur[i] = s;   // cursor; after scatter_k, cur[i] == segment end
    }
}

// ---------------- CSR build: scatter edges into dst-sorted order ------------
__global__ void scatter_k(const float* __restrict__ x, const int* __restrict__ src,
                          const int* __restrict__ dst, const float* __restrict__ ea,
                          const float* __restrict__ We1, const float* __restrict__ be1,
                          int* __restrict__ cur, int2* __restrict__ rec8,
                          float* __restrict__ m1s) {
    int e = blockIdx.x * blockDim.x + threadIdx.x;
    if (e >= N_EDGES) return;
    int s = src[e], d = dst[e];
    const float* ep = ea + (size_t)e * EAD;
    float p = be1[0];
#pragma unroll
    for (int k = 0; k < EAD; k++) p = fmaf(ep[k], We1[k], p);
    float m = x[s] + p;
    m = m > 0.0f ? m : 0.0f;
    int pos = atomicAdd(&cur[d], 1);
    rec8[pos] = make_int2(s, e);
    m1s[pos] = m;
}

// ---------------- conv1: segmented sum of m1 + fused MLP 1->64->64 ----------
__global__ void conv1_fused(const float* __restrict__ x, const float* __restrict__ m1s,
                            const int* __restrict__ off, const int* __restrict__ cur,
                            const float* __restrict__ W11, const float* __restrict__ b11,
                            const float* __restrict__ W12, const float* __restrict__ b12,
                            const float* __restrict__ eps1, float* __restrict__ hA) {
    __shared__ float sW12[H * H];
    __shared__ float stg[4][H];
    int tid = threadIdx.x;
    for (int i = tid; i < H * H; i += 256) sW12[i] = W12[i];
    int w = tid >> 6, lane = tid & 63;
    float rW11 = W11[lane], rb11 = b11[lane], rb12 = b12[lane], er = eps1[0];
    __syncthreads();
    int n0 = (blockIdx.x * 4 + w) * NPW1;
#pragma unroll
    for (int ni = 0; ni < NPW1; ni++) {
        int n = n0 + ni;
        int g0 = off[n], g1 = cur[n];
        float agg = 0.0f;
        for (int j = g0 + lane; j < g1; j += 64) agg += m1s[j];
#pragma unroll
        for (int o = 32; o > 0; o >>= 1) agg += __shfl_xor(agg, o, 64);
        float xv = x[n];
        float h1 = fmaf(er, xv, xv) + agg;
        float t = fmaf(h1, rW11, rb11);
        t = t > 0.0f ? t : 0.0f;
        stg[w][lane] = t;                  // intra-wave staging (lockstep)
        float acc = rb12;
#pragma unroll
        for (int j = 0; j < H; j++) acc = fmaf(stg[w][j], sW12[j * H + lane], acc);
        hA[(size_t)n * H + lane] = acc > 0.0f ? acc : 0.0f;
    }
}

// ---------------- conv2+heads mega-kernel (r7 structure, 8-deep gather) -----
// 256 threads, 69KB LDS, 2 blocks/CU (8 waves). r8 taught: more waves thrash
// L2 and shfl-transpose costs bank conflicts; the free resource is VGPRs
// (r7 used only 64 of ~256). So: 8-deep gather pipeline per wave - 8 s-index
// extractions + 8 hA-row loads issued before any consumption.
// Edge summation order identical to r7 (bitwise-same results).
__global__ void conv2_heads(const float* __restrict__ hA, const int2* __restrict__ rec8,
                            const float* __restrict__ ea, const int* __restrict__ batch,
                            const int* __restrict__ off, const int* __restrict__ cur,
                            const float* __restrict__ We2, const float* __restrict__ be2,
                            const float* __restrict__ W21, const float* __restrict__ b21,
                            const float* __restrict__ W22, const float* __restrict__ b22,
                            const float* __restrict__ eps2,
                            const float* __restrict__ Wmu, const float* __restrict__ bmu,
                            const float* __restrict__ Wlv, const float* __restrict__ blv,
                            float4* __restrict__ out4, float* __restrict__ zsum) {
    __shared__ float sW21[H * H], sW22[H * H];
    __shared__ float sWm[H * LAT], sWl[H * LAT];
    __shared__ float4 srec[4][64][2];
    __shared__ float stg[4][H];
    __shared__ float4 szout[4][3][NPWM][LAT / 4];
    int tid = threadIdx.x;
    for (int i = tid; i < H * H; i += 256) { sW21[i] = W21[i]; sW22[i] = W22[i]; }
    for (int i = tid; i < H * LAT; i += 256) { sWm[i] = Wmu[i]; sWl[i] = Wlv[i]; }
    int w = tid >> 6, lane = tid & 63;
    float rW[EAD];
#pragma unroll
    for (int k = 0; k < EAD; k++) rW[k] = We2[k * H + lane];
    float rbe2 = be2[lane], rb21 = b21[lane], rb22 = b22[lane], er = eps2[0];
    int l = lane & 31;
    float rbh = (lane < LAT) ? bmu[l] : blv[l];
    __syncthreads();

    int n0 = (blockIdx.x * 4 + w) * NPWM;
    int eend = cur[n0 + NPWM - 1];
    int sbase = -(1 << 30);

    auto restage = [&](int g) {
        sbase = g;
        int cnt = eend - g; cnt = cnt > 64 ? 64 : cnt;
        float a0 = 0, a1 = 0, a2 = 0, a3 = 0, a4 = 0, a5 = 0, a6 = 0;
        int s = 0;
        if (lane < cnt) {
            int2 r = rec8[g + lane];
            s = r.x;
            const float* ep = ea + (size_t)r.y * EAD;
            a0 = ep[0]; a1 = ep[1]; a2 = ep[2]; a3 = ep[3];
            a4 = ep[4]; a5 = ep[5]; a6 = ep[6];
        }
        srec[w][lane][0] = make_float4(a0, a1, a2, a3);
        srec[w][lane][1] = make_float4(a4, a5, a6, __int_as_float(s));
    };

    // per-edge body given LDS window slot b and prefetched hv
    auto edge_proj = [&](int b, float hv, float& acc) {
        float4 A = srec[w][b][0], B = srec[w][b][1];
        float p = rbe2;
        p = fmaf(A.x, rW[0], p); p = fmaf(A.y, rW[1], p);
        p = fmaf(A.z, rW[2], p); p = fmaf(A.w, rW[3], p);
        p = fmaf(B.x, rW[4], p); p = fmaf(B.y, rW[5], p);
        p = fmaf(B.z, rW[6], p);
        acc += fmaxf(hv + p, 0.0f);
    };

    for (int ni = 0; ni < NPWM; ni++) {
        int n = n0 + ni;
        int g = off[n], gend = cur[n];
        float acc = 0.0f;
        // -------- 8-deep main stage: issue 8 row loads before consuming ----
        while (g + 8 <= gend) {
            if (g + 8 > sbase + 64) restage(g);
            int b = g - sbase;
            int s0 = __builtin_amdgcn_readfirstlane(__float_as_int(((const float*)&srec[w][b + 0][1])[3]));
            int s1 = __builtin_amdgcn_readfirstlane(__float_as_int(((const float*)&srec[w][b + 1][1])[3]));
            int s2 = __builtin_amdgcn_readfirstlane(__float_as_int(((const float*)&srec[w][b + 2][1])[3]));
            int s3 = __builtin_amdgcn_readfirstlane(__float_as_int(((const float*)&srec[w][b + 3][1])[3]));
            int s4 = __builtin_amdgcn_readfirstlane(__float_as_int(((const float*)&srec[w][b + 4][1])[3]));
            int s5 = __builtin_amdgcn_readfirstlane(__float_as_int(((const float*)&srec[w][b + 5][1])[3]));
            int s6 = __builtin_amdgcn_readfirstlane(__float_as_int(((const float*)&srec[w][b + 6][1])[3]));
            int s7 = __builtin_amdgcn_readfirstlane(__float_as_int(((const float*)&srec[w][b + 7][1])[3]));
            float hv0 = hA[(size_t)s0 * H + lane];
            float hv1 = hA[(size_t)s1 * H + lane];
            float hv2 = hA[(size_t)s2 * H + lane];
            float hv3 = hA[(size_t)s3 * H + lane];
            float hv4 = hA[(size_t)s4 * H + lane];
            float hv5 = hA[(size_t)s5 * H + lane];
            float hv6 = hA[(size_t)s6 * H + lane];
            float hv7 = hA[(size_t)s7 * H + lane];
            edge_proj(b + 0, hv0, acc);
            edge_proj(b + 1, hv1, acc);
            edge_proj(b + 2, hv2, acc);
            edge_proj(b + 3, hv3, acc);
            edge_proj(b + 4, hv4, acc);
            edge_proj(b + 5, hv5, acc);
            edge_proj(b + 6, hv6, acc);
            edge_proj(b + 7, hv7, acc);
            g += 8;
        }
        // -------- 4-deep mid stage -----------------------------------------
        while (g + 4 <= gend) {
            if (g + 4 > sbase + 64) restage(g);
            int b = g - sbase;
            int s0 = __builtin_amdgcn_readfirstlane(__float_as_int(((const float*)&srec[w][b + 0][1])[3]));
            int s1 = __builtin_amdgcn_readfirstlane(__float_as_int(((const float*)&srec[w][b + 1][1])[3]));
            int s2 = __builtin_amdgcn_readfirstlane(__float_as_int(((const float*)&srec[w][b + 2][1])[3]));
            int s3 = __builtin_amdgcn_readfirstlane(__float_as_int(((const float*)&srec[w][b + 3][1])[3]));
            float hv0 = hA[(size_t)s0 * H + lane];
            float hv1 = hA[(size_t)s1 * H + lane];
            float hv2 = hA[(size_t)s2 * H + lane];
            float hv3 = hA[(size_t)s3 * H + lane];
            edge_proj(b + 0, hv0, acc);
            edge_proj(b + 1, hv1, acc);
            edge_proj(b + 2, hv2, acc);
            edge_proj(b + 3, hv3, acc);
            g += 4;
        }
        // -------- scalar tail ----------------------------------------------
        while (g < gend) {
            if (g >= sbase + 64) restage(g);
            int b = g - sbase;
            int s = __builtin_amdgcn_readfirstlane(__float_as_int(((const float*)&srec[w][b][1])[3]));
            float hv = hA[(size_t)s * H + lane];
            edge_proj(b, hv, acc);
            g++;
        }
        // fused 2-layer MLP (wave-synchronous LDS staging)
        float hself = hA[(size_t)n * H + lane];
        float h2 = fmaf(er, hself, hself) + acc;
        stg[w][lane] = h2;
        float t = rb21;
#pragma unroll
        for (int j = 0; j < H; j++) t = fmaf(stg[w][j], sW21[j * H + lane], t);
        t = t > 0.0f ? t : 0.0f;
        stg[w][lane] = t;
        float o2 = rb22;
#pragma unroll
        for (int j = 0; j < H; j++) o2 = fmaf(stg[w][j], sW22[j * H + lane], o2);
        o2 = o2 > 0.0f ? o2 : 0.0f;
        stg[w][lane] = o2;                 // hB row, lane = feature
        // heads GEMV: lanes 0-31 compute mu[l], lanes 32-63 compute lv[l]
        const float* Wh = (lane < LAT) ? sWm : sWl;
        float v = rbh;
#pragma unroll
        for (int j = 0; j < H; j++) v = fmaf(stg[w][j], Wh[j * LAT + l], v);
        float o = __shfl(v, lane ^ 32);    // low: o=lv ; high: o=mu
        if (lane < LAT) {
            float muv = v, lvv = o;
            int i = n * LAT + l;
            uint32_t x0 = 0u, x1 = (uint32_t)i;
            threefry2x32_42(x0, x1);
            uint32_t bits = x0 ^ x1;
            float f = __uint_as_float((bits >> 9) | 0x3F800000u) - 1.0f;
            const float lo = -0.99999994f;
            float u = fmaxf(lo, fmaf(f, 2.0f, lo));
            float noise = 1.41421356237309515f * erfinv_f32(u);
            float z = fmaf(noise, expf(0.5f * lvv), muv);
            float* zp = (float*)&szout[w][0][ni][0];
            float* mp = (float*)&szout[w][1][ni][0];
            float* lp = (float*)&szout[w][2][ni][0];
            zp[l] = z; mp[l] = muv; lp[l] = lvv;
            atomicAdd(&zsum[batch[n] * LAT + l], z);
        }
    }
    // batched wave-synchronous float4 stores: 1KB contiguous per array
    int nl = lane >> 3, f4 = lane & 7;
#pragma unroll
    for (int it = 0; it < 3; it++)
        out4[(size_t)it * (NZ / 4) + (size_t)(n0 + nl) * 8 + f4] = szout[w][it][nl][f4];
}

// ---------------- pool + logits from zsum; batch SORTED ---------------------
__global__ void pool2_k(const float* __restrict__ zsum, const int* __restrict__ batch,
                        const float* __restrict__ Wc, const float* __restrict__ bc,
                        float* __restrict__ out) {
    __shared__ float emb[LAT];
    int g = blockIdx.x, tid = threadIdx.x;
    int lo = 0, hi = N_NODES;
    while (lo < hi) { int mid = (lo + hi) >> 1; if (batch[mid] < g) lo = mid + 1; else hi = mid; }
    int start = lo;
    hi = N_NODES;
    while (lo < hi) { int mid = (lo + hi) >> 1; if (batch[mid] < g + 1) lo = mid + 1; else hi = mid; }
    int end = lo;
    if (tid < LAT) {
        float invc = 1.0f / fmaxf((float)(end - start), 1.0f);
        emb[tid] = zsum[g * LAT + tid] * invc;
    }
    __syncthreads();
    if (tid < NC) {
        float r = bc[tid];
#pragma unroll
        for (int l = 0; l < LAT; l++) r = fmaf(emb[l], Wc[l * NC + tid], r);
        out[g * NC + tid] = r;
    }
}

extern "C" void kernel_launch(void* const* d_in, const int* in_sizes, int n_in,
                              void* d_out, int out_size, void* d_ws, size_t ws_size,
                              hipStream_t stream) {
    const float* x     = (const float*)d_in[0];
    const int*   ei    = (const int*)d_in[1];
    const float* ea    = (const float*)d_in[2];
    const int*   batch = (const int*)d_in[3];
    const float* We1   = (const float*)d_in[4];
    const float* be1   = (const float*)d_in[5];
    const float* W11   = (const float*)d_in[6];
    const float* b11   = (const float*)d_in[7];
    const float* W12   = (const float*)d_in[8];
    const float* b12   = (const float*)d_in[9];
    const float* eps1  = (const float*)d_in[10];
    const float* We2   = (const float*)d_in[11];
    const float* be2   = (const float*)d_in[12];
    const float* W21   = (const float*)d_in[13];
    const float* b21   = (const float*)d_in[14];
    const float* W22   = (const float*)d_in[15];
    const float* b22   = (const float*)d_in[16];
    const float* eps2  = (const float*)d_in[17];
    const float* Wmu   = (const float*)d_in[18];
    const float* bmu   = (const float*)d_in[19];
    const float* Wlv   = (const float*)d_in[20];
    const float* blv   = (const float*)d_in[21];
    const float* Wc    = (const float*)d_in[22];
    const float* bc    = (const float*)d_in[23];

    // ws layout (46.07 MB, inside the proven 51.6 MB budget):
    //   [zsum G*LAT]                          0.065 MB (zeroed each launch)
    //   [deg N][off N][cur N][bsum 512]       1.20 MB
    //   [rec8 E int2]                        12.80 MB
    //   [m1s E float]                         6.40 MB
    //   [hA  N*H float]                      25.60 MB
    float* zsum = (float*)d_ws;
    int*   deg  = (int*)d_ws + NG * LAT;
    int*   off  = deg + N_NODES;
    int*   cur  = off + N_NODES;
    int*   bsum = cur + N_NODES;
    int2*  rec8 = (int2*)(bsum + 512);
    float* m1s  = (float*)(rec8 + N_EDGES);
    float* hA   = m1s + N_EDGES;
    float* outf = (float*)d_out;

    // zero zsum + deg (contiguous)
    hipMemsetAsync(d_ws, 0, (size_t)(NG * LAT + N_NODES) * sizeof(float), stream);

    const int* src = ei;
    const int* dst = ei + N_EDGES;

    hist_k<<<N_EDGES / 256, 256, 0, stream>>>(dst, deg);
    scan1_k<<<NB_SCAN, 256, 0, stream>>>(deg, bsum);
    scan2_k<<<1, 512, 0, stream>>>(bsum);
    scan3_k<<<NB_SCAN, 256, 0, stream>>>(deg, bsum, off, cur);
    scatter_k<<<N_EDGES / 256, 256, 0, stream>>>(x, src, dst, ea, We1, be1, cur, rec8, m1s);
    conv1_fused<<<N_NODES / (4 * NPW1), 256, 0, stream>>>(
        x, m1s, off, cur, W11, b11, W12, b12, eps1, hA);
    conv2_heads<<<N_NODES / (4 * NPWM), 256, 0, stream>>>(
        hA, rec8, ea, batch, off, cur, We2, be2, W21, b21, W22, b22, eps2,
        Wmu, bmu, Wlv, blv, (float4*)outf, zsum);
    pool2_k<<<NG, 64, 0, stream>>>(zsum, batch, Wc, bc, outf + 3 * (size_t)NZ);
}

// Round 10
// 877.702 us; speedup vs baseline: 1.2705x; 1.1692x over previous
//
#include <hip/hip_runtime.h>
#include <stdint.h>

#define N_NODES 100000
#define N_EDGES 1600000
#define EAD 7
#define H 64
#define LAT 32
#define NG 512
#define NC 6
#define NZ (N_NODES * LAT)

#define NB_SCAN 391            // ceil(N_NODES/256)
#define C1_NPB 32              // nodes per block, conv1_node
#define NPWM 8                 // nodes per wave, conv2_heads (3125 blocks x 4 waves)

static_assert(N_NODES % C1_NPB == 0, "conv1_node grid exact");
static_assert(N_NODES % (4 * NPWM) == 0, "conv2_heads grid exact");
static_assert(N_EDGES % 256 == 0, "edge grid exact");

// ---------------- Threefry-2x32-20, key = (0, 42)  (jax.random.key(42)) ----
__device__ __forceinline__ void threefry2x32_42(uint32_t& x0, uint32_t& x1) {
    const uint32_t k0 = 0u, k1 = 42u;
    const uint32_t k2 = k0 ^ k1 ^ 0x1BD11BDAu;
    x0 += k0; x1 += k1;
#define TF_ROUND(r) { x0 += x1; x1 = (x1 << (r)) | (x1 >> (32 - (r))); x1 ^= x0; }
    TF_ROUND(13) TF_ROUND(15) TF_ROUND(26) TF_ROUND(6)
    x0 += k1; x1 += k2 + 1u;
    TF_ROUND(17) TF_ROUND(29) TF_ROUND(16) TF_ROUND(24)
    x0 += k2; x1 += k0 + 2u;
    TF_ROUND(13) TF_ROUND(15) TF_ROUND(26) TF_ROUND(6)
    x0 += k0; x1 += k1 + 3u;
    TF_ROUND(17) TF_ROUND(29) TF_ROUND(16) TF_ROUND(24)
    x0 += k1; x1 += k2 + 4u;
    TF_ROUND(13) TF_ROUND(15) TF_ROUND(26) TF_ROUND(6)
    x0 += k2; x1 += k0 + 5u;
#undef TF_ROUND
}

// XLA f32 ErfInv (Giles): matches jax.lax.erf_inv on f32
__device__ __forceinline__ float erfinv_f32(float x) {
    float w = -log1pf(-x * x);
    float p;
    if (w < 5.0f) {
        w = w - 2.5f;
        p = 2.81022636e-08f;
        p = fmaf(p, w, 3.43273939e-07f);
        p = fmaf(p, w, -3.5233877e-06f);
        p = fmaf(p, w, -4.39150654e-06f);
        p = fmaf(p, w, 0.00021858087f);
        p = fmaf(p, w, -0.00125372503f);
        p = fmaf(p, w, -0.00417768164f);
        p = fmaf(p, w, 0.246640727f);
        p = fmaf(p, w, 1.50140941f);
    } else {
        w = sqrtf(w) - 3.0f;
        p = -0.000200214257f;
        p = fmaf(p, w, 0.000100950558f);
        p = fmaf(p, w, 0.00134934322f);
        p = fmaf(p, w, -0.00367342844f);
        p = fmaf(p, w, 0.00573950773f);
        p = fmaf(p, w, -0.0076224613f);
        p = fmaf(p, w, 0.00943887047f);
        p = fmaf(p, w, 1.00167406f);
        p = fmaf(p, w, 2.83297682f);
    }
    return p * x;
}

// ---------------- conv1 edge pass + inline histogram ------------------------
// r0-proven scalar atomics (1.6M adds onto 100K floats); deg folded in so the
// separate hist kernel disappears.
__global__ void conv1_edge(const float* __restrict__ x, const int* __restrict__ src,
                           const int* __restrict__ dst, const float* __restrict__ ea,
                           const float* __restrict__ We1, const float* __restrict__ be1,
                           float* __restrict__ agg1, int* __restrict__ deg) {
    int e = blockIdx.x * blockDim.x + threadIdx.x;
    if (e >= N_EDGES) return;
    int s = src[e], d = dst[e];
    const float* ep = ea + (size_t)e * EAD;
    float p = be1[0];
#pragma unroll
    for (int k = 0; k < EAD; k++) p = fmaf(ep[k], We1[k], p);
    float m = x[s] + p;
    m = m > 0.0f ? m : 0.0f;
    atomicAdd(&agg1[d], m);
    atomicAdd(&deg[d], 1);
}

// ---------------- conv1 node MLP 1->64->64 (r0-proven, wave-synchronous) ----
__global__ void conv1_node(const float* __restrict__ x, const float* __restrict__ agg1,
                           const float* __restrict__ W11, const float* __restrict__ b11,
                           const float* __restrict__ W12, const float* __restrict__ b12,
                           const float* __restrict__ eps1, float* __restrict__ hA) {
    __shared__ float sW12[H * H];
    __shared__ float stg[4][H];
    int tid = threadIdx.x;
    for (int i = tid; i < H * H; i += 256) sW12[i] = W12[i];
    int w = tid >> 6, lane = tid & 63;
    float rW11 = W11[lane], rb11 = b11[lane], rb12 = b12[lane], er = eps1[0];
    __syncthreads();
#pragma unroll
    for (int it = 0; it < C1_NPB / 4; it++) {
        int n = blockIdx.x * C1_NPB + it * 4 + w;
        float xv = x[n];
        float h1 = fmaf(er, xv, xv) + agg1[n];
        float t = fmaf(h1, rW11, rb11);
        t = t > 0.0f ? t : 0.0f;
        stg[w][lane] = t;                  // intra-wave staging (lockstep)
        float acc = rb12;
#pragma unroll
        for (int j = 0; j < H; j++) acc = fmaf(stg[w][j], sW12[j * H + lane], acc);
        hA[(size_t)n * H + lane] = acc > 0.0f ? acc : 0.0f;
    }
}

// ---------------- CSR build: 3-pass exclusive scan over deg -----------------
__global__ void scan1_k(const int* __restrict__ deg, int* __restrict__ bsum) {
    __shared__ int sv[256];
    int t = threadIdx.x, i = blockIdx.x * 256 + t;
    sv[t] = (i < N_NODES) ? deg[i] : 0;
    __syncthreads();
    for (int o = 128; o > 0; o >>= 1) {
        if (t < o) sv[t] += sv[t + o];
        __syncthreads();
    }
    if (t == 0) bsum[blockIdx.x] = sv[0];
}

__global__ void scan2_k(int* __restrict__ bsum) {
    __shared__ int sv[512];
    int t = threadIdx.x;
    int v = (t < NB_SCAN) ? bsum[t] : 0;
    sv[t] = v;
    __syncthreads();
    for (int o = 1; o < 512; o <<= 1) {
        int a = (t >= o) ? sv[t - o] : 0;
        __syncthreads();
        sv[t] += a;
        __syncthreads();
    }
    if (t < NB_SCAN) bsum[t] = sv[t] - v;   // exclusive block offsets
}

__global__ void scan3_k(const int* __restrict__ deg, const int* __restrict__ bsum,
                        int* __restrict__ off, int* __restrict__ cur) {
    __shared__ int sv[256];
    int t = threadIdx.x, i = blockIdx.x * 256 + t;
    int v = (i < N_NODES) ? deg[i] : 0;
    sv[t] = v;
    __syncthreads();
    for (int o = 1; o < 256; o <<= 1) {
        int a = (t >= o) ? sv[t - o] : 0;
        __syncthreads();
        sv[t] += a;
        __syncthreads();
    }
    if (i < N_NODES) {
        int s = bsum[blockIdx.x] + sv[t] - v;
        off[i] = s;
        cur[i] = s;   // cursor; after scatter_lite, cur[i] == segment end
    }
}

// ---------------- CSR build: scatter (s,e) records only ---------------------
// No ea read, no m1s write (conv1 handled by atomics) -> minimal traffic.
__global__ void scatter_lite(const int* __restrict__ src, const int* __restrict__ dst,
                             int* __restrict__ cur, int2* __restrict__ rec8) {
    int e = blockIdx.x * blockDim.x + threadIdx.x;
    if (e >= N_EDGES) return;
    int s = src[e], d = dst[e];
    int pos = atomicAdd(&cur[d], 1);
    rec8[pos] = make_int2(s, e);
}

// ---------------- conv2+heads mega-kernel (r7 EXACT, 433us proven) ----------
// 256 threads, 69KB LDS, 2 blocks/CU. r8 (more waves) and r9 (deeper
// pipeline) both regressed with FETCH increases -> this shape is the
// empirical optimum for the random-row gather. Do not touch.
__global__ void conv2_heads(const float* __restrict__ hA, const int2* __restrict__ rec8,
                            const float* __restrict__ ea, const int* __restrict__ batch,
                            const int* __restrict__ off, const int* __restrict__ cur,
                            const float* __restrict__ We2, const float* __restrict__ be2,
                            const float* __restrict__ W21, const float* __restrict__ b21,
                            const float* __restrict__ W22, const float* __restrict__ b22,
                            const float* __restrict__ eps2,
                            const float* __restrict__ Wmu, const float* __restrict__ bmu,
                            const float* __restrict__ Wlv, const float* __restrict__ blv,
                            float4* __restrict__ out4, float* __restrict__ zsum) {
    __shared__ float sW21[H * H], sW22[H * H];
    __shared__ float sWm[H * LAT], sWl[H * LAT];
    __shared__ float4 srec[4][64][2];
    __shared__ float stg[4][H];
    __shared__ float4 szout[4][3][NPWM][LAT / 4];
    int tid = threadIdx.x;
    for (int i = tid; i < H * H; i += 256) { sW21[i] = W21[i]; sW22[i] = W22[i]; }
    for (int i = tid; i < H * LAT; i += 256) { sWm[i] = Wmu[i]; sWl[i] = Wlv[i]; }
    int w = tid >> 6, lane = tid & 63;
    float rW[EAD];
#pragma unroll
    for (int k = 0; k < EAD; k++) rW[k] = We2[k * H + lane];
    float rbe2 = be2[lane], rb21 = b21[lane], rb22 = b22[lane], er = eps2[0];
    int l = lane & 31;
    float rbh = (lane < LAT) ? bmu[l] : blv[l];
    __syncthreads();

    int n0 = (blockIdx.x * 4 + w) * NPWM;
    int eend = cur[n0 + NPWM - 1];
    int sbase = -(1 << 30);

    auto restage = [&](int g) {
        sbase = g;
        int cnt = eend - g; cnt = cnt > 64 ? 64 : cnt;
        float a0 = 0, a1 = 0, a2 = 0, a3 = 0, a4 = 0, a5 = 0, a6 = 0;
        int s = 0;
        if (lane < cnt) {
            int2 r = rec8[g + lane];
            s = r.x;
            const float* ep = ea + (size_t)r.y * EAD;
            a0 = ep[0]; a1 = ep[1]; a2 = ep[2]; a3 = ep[3];
            a4 = ep[4]; a5 = ep[5]; a6 = ep[6];
        }
        srec[w][lane][0] = make_float4(a0, a1, a2, a3);
        srec[w][lane][1] = make_float4(a4, a5, a6, __int_as_float(s));
    };

    for (int ni = 0; ni < NPWM; ni++) {
        int n = n0 + ni;
        int g = off[n], gend = cur[n];
        float acc = 0.0f;
        while (g + 4 <= gend) {
            if (g + 4 > sbase + 64) restage(g);
            int b = g - sbase;
            float4 A0 = srec[w][b + 0][0], B0 = srec[w][b + 0][1];
            float4 A1 = srec[w][b + 1][0], B1 = srec[w][b + 1][1];
            float4 A2 = srec[w][b + 2][0], B2 = srec[w][b + 2][1];
            float4 A3 = srec[w][b + 3][0], B3 = srec[w][b + 3][1];
            int s0 = __builtin_amdgcn_readfirstlane(__float_as_int(B0.w));
            int s1 = __builtin_amdgcn_readfirstlane(__float_as_int(B1.w));
            int s2 = __builtin_amdgcn_readfirstlane(__float_as_int(B2.w));
            int s3 = __builtin_amdgcn_readfirstlane(__float_as_int(B3.w));
            float hv0 = hA[(size_t)s0 * H + lane];
            float hv1 = hA[(size_t)s1 * H + lane];
            float hv2 = hA[(size_t)s2 * H + lane];
            float hv3 = hA[(size_t)s3 * H + lane];
            float p0 = rbe2, p1 = rbe2, p2 = rbe2, p3 = rbe2;
            p0 = fmaf(A0.x, rW[0], p0); p0 = fmaf(A0.y, rW[1], p0);
            p0 = fmaf(A0.z, rW[2], p0); p0 = fmaf(A0.w, rW[3], p0);
            p0 = fmaf(B0.x, rW[4], p0); p0 = fmaf(B0.y, rW[5], p0);
            p0 = fmaf(B0.z, rW[6], p0);
            p1 = fmaf(A1.x, rW[0], p1); p1 = fmaf(A1.y, rW[1], p1);
            p1 = fmaf(A1.z, rW[2], p1); p1 = fmaf(A1.w, rW[3], p1);
            p1 = fmaf(B1.x, rW[4], p1); p1 = fmaf(B1.y, rW[5], p1);
            p1 = fmaf(B1.z, rW[6], p1);
            p2 = fmaf(A2.x, rW[0], p2); p2 = fmaf(A2.y, rW[1], p2);
            p2 = fmaf(A2.z, rW[2], p2); p2 = fmaf(A2.w, rW[3], p2);
            p2 = fmaf(B2.x, rW[4], p2); p2 = fmaf(B2.y, rW[5], p2);
            p2 = fmaf(B2.z, rW[6], p2);
            p3 = fmaf(A3.x, rW[0], p3); p3 = fmaf(A3.y, rW[1], p3);
            p3 = fmaf(A3.z, rW[2], p3); p3 = fmaf(A3.w, rW[3], p3);
            p3 = fmaf(B3.x, rW[4], p3); p3 = fmaf(B3.y, rW[5], p3);
            p3 = fmaf(B3.z, rW[6], p3);
            acc += fmaxf(hv0 + p0, 0.0f);
            acc += fmaxf(hv1 + p1, 0.0f);
            acc += fmaxf(hv2 + p2, 0.0f);
            acc += fmaxf(hv3 + p3, 0.0f);
            g += 4;
        }
        while (g < gend) {
            if (g >= sbase + 64) restage(g);
            int b = g - sbase;
            float4 A = srec[w][b][0], B = srec[w][b][1];
            int s = __builtin_amdgcn_readfirstlane(__float_as_int(B.w));
            float hv = hA[(size_t)s * H + lane];
            float p = rbe2;
            p = fmaf(A.x, rW[0], p); p = fmaf(A.y, rW[1], p);
            p = fmaf(A.z, rW[2], p); p = fmaf(A.w, rW[3], p);
            p = fmaf(B.x, rW[4], p); p = fmaf(B.y, rW[5], p);
            p = fmaf(B.z, rW[6], p);
            acc += fmaxf(hv + p, 0.0f);
            g++;
        }
        // fused 2-layer MLP (wave-synchronous LDS staging)
        float hself = hA[(size_t)n * H + lane];
        float h2 = fmaf(er, hself, hself) + acc;
        stg[w][lane] = h2;
        float t = rb21;
#pragma unroll
        for (int j = 0; j < H; j++) t = fmaf(stg[w][j], sW21[j * H + lane], t);
        t = t > 0.0f ? t : 0.0f;
        stg[w][lane] = t;
        float o2 = rb22;
#pragma unroll
        for (int j = 0; j < H; j++) o2 = fmaf(stg[w][j], sW22[j * H + lane], o2);
        o2 = o2 > 0.0f ? o2 : 0.0f;
        stg[w][lane] = o2;                 // hB row, lane = feature
        // heads GEMV: lanes 0-31 compute mu[l], lanes 32-63 compute lv[l]
        const float* Wh = (lane < LAT) ? sWm : sWl;
        float v = rbh;
#pragma unroll
        for (int j = 0; j < H; j++) v = fmaf(stg[w][j], Wh[j * LAT + l], v);
        float o = __shfl(v, lane ^ 32);    // low: o=lv ; high: o=mu
        if (lane < LAT) {
            float muv = v, lvv = o;
            int i = n * LAT + l;
            uint32_t x0 = 0u, x1 = (uint32_t)i;
            threefry2x32_42(x0, x1);
            uint32_t bits = x0 ^ x1;
            float f = __uint_as_float((bits >> 9) | 0x3F800000u) - 1.0f;
            const float lo = -0.99999994f;
            float u = fmaxf(lo, fmaf(f, 2.0f, lo));
            float noise = 1.41421356237309515f * erfinv_f32(u);
            float z = fmaf(noise, expf(0.5f * lvv), muv);
            float* zp = (float*)&szout[w][0][ni][0];
            float* mp = (float*)&szout[w][1][ni][0];
            float* lp = (float*)&szout[w][2][ni][0];
            zp[l] = z; mp[l] = muv; lp[l] = lvv;
            atomicAdd(&zsum[batch[n] * LAT + l], z);
        }
    }
    // batched wave-synchronous float4 stores: 1KB contiguous per array
    int nl = lane >> 3, f4 = lane & 7;
#pragma unroll
    for (int it = 0; it < 3; it++)
        out4[(size_t)it * (NZ / 4) + (size_t)(n0 + nl) * 8 + f4] = szout[w][it][nl][f4];
}

// ---------------- pool + logits from zsum; batch SORTED ---------------------
__global__ void pool2_k(const float* __restrict__ zsum, const int* __restrict__ batch,
                        const float* __restrict__ Wc, const float* __restrict__ bc,
                        float* __restrict__ out) {
    __shared__ float emb[LAT];
    int g = blockIdx.x, tid = threadIdx.x;
    int lo = 0, hi = N_NODES;
    while (lo < hi) { int mid = (lo + hi) >> 1; if (batch[mid] < g) lo = mid + 1; else hi = mid; }
    int start = lo;
    hi = N_NODES;
    while (lo < hi) { int mid = (lo + hi) >> 1; if (batch[mid] < g + 1) lo = mid + 1; else hi = mid; }
    int end = lo;
    if (tid < LAT) {
        float invc = 1.0f / fmaxf((float)(end - start), 1.0f);
        emb[tid] = zsum[g * LAT + tid] * invc;
    }
    __syncthreads();
    if (tid < NC) {
        float r = bc[tid];
#pragma unroll
        for (int l = 0; l < LAT; l++) r = fmaf(emb[l], Wc[l * NC + tid], r);
        out[g * NC + tid] = r;
    }
}

extern "C" void kernel_launch(void* const* d_in, const int* in_sizes, int n_in,
                              void* d_out, int out_size, void* d_ws, size_t ws_size,
                              hipStream_t stream) {
    const float* x     = (const float*)d_in[0];
    const int*   ei    = (const int*)d_in[1];
    const float* ea    = (const float*)d_in[2];
    const int*   batch = (const int*)d_in[3];
    const float* We1   = (const float*)d_in[4];
    const float* be1   = (const float*)d_in[5];
    const float* W11   = (const float*)d_in[6];
    const float* b11   = (const float*)d_in[7];
    const float* W12   = (const float*)d_in[8];
    const float* b12   = (const float*)d_in[9];
    const float* eps1  = (const float*)d_in[10];
    const float* We2   = (const float*)d_in[11];
    const float* be2   = (const float*)d_in[12];
    const float* W21   = (const float*)d_in[13];
    const float* b21   = (const float*)d_in[14];
    const float* W22   = (const float*)d_in[15];
    const float* b22   = (const float*)d_in[16];
    const float* eps2  = (const float*)d_in[17];
    const float* Wmu   = (const float*)d_in[18];
    const float* bmu   = (const float*)d_in[19];
    const float* Wlv   = (const float*)d_in[20];
    const float* blv   = (const float*)d_in[21];
    const float* Wc    = (const float*)d_in[22];
    const float* bc    = (const float*)d_in[23];

    // ws layout (40.1 MB, well inside the proven 46 MB footprint):
    //   [zsum G*LAT f32]                      0.065 MB \ zeroed together
    //   [agg1 N f32]                          0.40 MB  | with deg
    //   [deg N i32]                           0.40 MB  /
    //   [off N][cur N][bsum 512]              0.80 MB
    //   [rec8 E int2]                        12.80 MB
    //   [hA  N*H f32]                        25.60 MB
    // m1s buffer and hist kernel are gone: conv1 aggregates via scalar
    // atomics (r0-proven), deg is folded into conv1_edge.
    float* zsum = (float*)d_ws;
    float* agg1 = zsum + NG * LAT;
    int*   deg  = (int*)(agg1 + N_NODES);
    int*   off  = deg + N_NODES;
    int*   cur  = off + N_NODES;
    int*   bsum = cur + N_NODES;
    int2*  rec8 = (int2*)(bsum + 512);
    float* hA   = (float*)(rec8 + N_EDGES);
    float* outf = (float*)d_out;

    // zero zsum + agg1 + deg (contiguous)
    hipMemsetAsync(d_ws, 0, (size_t)(NG * LAT + 2 * N_NODES) * sizeof(float), stream);

    const int* src = ei;
    const int* dst = ei + N_EDGES;

    conv1_edge<<<N_EDGES / 256, 256, 0, stream>>>(x, src, dst, ea, We1, be1, agg1, deg);
    conv1_node<<<N_NODES / C1_NPB, 256, 0, stream>>>(
        x, agg1, W11, b11, W12, b12, eps1, hA);
    scan1_k<<<NB_SCAN, 256, 0, stream>>>(deg, bsum);
    scan2_k<<<1, 512, 0, stream>>>(bsum);
    scan3_k<<<NB_SCAN, 256, 0, stream>>>(deg, bsum, off, cur);
    scatter_lite<<<N_EDGES / 256, 256, 0, stream>>>(src, dst, cur, rec8);
    conv2_heads<<<N_NODES / (4 * NPWM), 256, 0, stream>>>(
        hA, rec8, ea, batch, off, cur, We2, be2, W21, b21, W22, b22, eps2,
        Wmu, bmu, Wlv, blv, (float4*)outf, zsum);
    pool2_k<<<NG, 64, 0, stream>>>(zsum, batch, Wc, bc, outf + 3 * (size_t)NZ);
}